// Round 15
// baseline (77.166 us; speedup 1.0000x reference)
//
#include <hip/hip_runtime.h>
#include <hip/hip_bf16.h>

typedef __attribute__((ext_vector_type(8))) short short8;
typedef __attribute__((ext_vector_type(4))) short s16x4;
typedef __attribute__((ext_vector_type(4))) float f32x4;

#define NB_H 96
#define NB_W 128
#define NB_D 32
#define NB_C 16
#define NB_F 16
#define NPIX (2 * NB_H * NB_W)                 // 24576
#define KB2_U16 (14 * 512)                     // 7168 u16 = 14336 B
#define WS_NEED ((size_t)KB2_U16 * 2)
#define SLAB_STRIDE 1280                       // 32 rows * 40 B
#define NSLAB 36                               // 6h x 6w (4x4 tile + halo)
#define DV_OFF (NSLAB * SLAB_STRIDE)           // 46080
#define LDS_BYTES (DV_OFF + 64)                // 46144

// fp32 -> bf16 RNE
static __device__ __forceinline__ short fcvt(float f) {
  return (short)__builtin_bit_cast(unsigned short, __float2bfloat16(f));
}

// Pair table: p=3q+m (q=0..3): m=0 -> taps(6q,6q+1) [UNIF n=2q, kd=0/1];
// m=1 -> (6q+3,6q+4) [UNIF n=2q+1]; m=2 -> (6q+2,6q+5) [MIX kd=2].
// p=12 -> (24,25) [UNIF n=8]. p=13 -> (26,pad). tap t = n*3+kd.

// ---- weights prep: kern fp32 -> bf16 B-frag layout [p][grp][f][j] ---------
__global__ __launch_bounds__(256) void sconv3d_wprep(
    const float* __restrict__ kern, unsigned short* __restrict__ kb2) {
  const int i = blockIdx.x * 256 + threadIdx.x;
  if (i >= KB2_U16) return;
  const int p = i >> 9;
  const int g = (i >> 7) & 3;
  const int f = (i >> 3) & 15;
  const int j = i & 7;
  const int k = g * 8 + j;
  int lo, hi;
  if (p < 12) {
    const int q = p / 3, m = p % 3;
    lo = (m == 0) ? 6 * q : (m == 1) ? 6 * q + 3 : 6 * q + 2;
    hi = (m == 0) ? 6 * q + 1 : (m == 1) ? 6 * q + 4 : 6 * q + 5;
  } else if (p == 12) { lo = 24; hi = 25; }
  else { lo = 26; hi = -1; }
  const int t = (k < 16) ? lo : hi;
  const int c = k & 15;
  kb2[i] = (t >= 0) ? (unsigned short)fcvt(kern[(t * 16 + c) * 16 + f])
                    : (unsigned short)0;
}

// ---- main: 4x4 tile, 256 thr, wave = 4 px (one h-row), bf via LDS barrier -
__global__ __launch_bounds__(256, 3) void sconv3d_fused7(
    const float* __restrict__ img, const int* __restrict__ bp,
    const unsigned short* __restrict__ kb2, const float* __restrict__ dvp,
    float* __restrict__ out) {
  __shared__ char Sb[LDS_BYTES];
  const int tid = threadIdx.x;
  const int lane = tid & 63;
  const int r = lane & 15;          // A: d row; B/D: f column
  const int grp = lane >> 4;        // 0..3
  const int vc = (grp & 1) * 16;    // byte offset of c-slice within 32B row
  const int halfbit = grp >> 1;     // K half: 0 -> tap lo, 1 -> tap hi
  const int rA = r + halfbit - 1;   // UNIF d row pre-rel
  const int rX = r + 1;             // MIX d row pre-rel
  const int rA40 = rA * 40 + vc;
  const int rX40 = rX * 40 + vc;
  const int voff_dv = DV_OFF + vc;

  // tile decode, XCD-chunked bijective swizzle: 1536 = 8 * 192
  const int bid = (blockIdx.x & 7) * 192 + (blockIdx.x >> 3);
  const int b = bid >= 768;
  const int rem = bid - b * 768;
  const int h0 = (rem >> 5) * 4;              // 24 h-tiles
  const int w0 = (rem & 31) * 4;              // 32 w-tiles

  // ---- issue bf copy loads, then 18 staging loads (deep MLP) ----
  int4 bfw[4];
  {
    const int4* kbsrc = (const int4*)kb2;
#pragma unroll
    for (int i = 0; i < 4; ++i) {
      const int idx = tid + i * 256;
      if (idx < KB2_U16 / 8) bfw[i] = kbsrc[idx];
    }
  }
  const int sg = __builtin_amdgcn_readfirstlane((int)(tid >> 7));  // 0..1
  const int q = tid & 127;
  float4 stv[18];
#pragma unroll
  for (int k = 0; k < 18; ++k) {
    const int s = 2 * k + sg;                 // slab 0..35
    const int dh = s / 6, dw = s - 6 * dh;
    const int hh = min(max(h0 + dh - 1, 0), NB_H - 1);
    const int ww = min(max(w0 + dw - 1, 0), NB_W - 1);
    stv[k] = *(const float4*)(
        img + ((b * NB_H + hh) * NB_W + ww) * (NB_D * NB_C) + q * 4);
  }

  // ---- bf -> LDS (region later overwritten by slabs) ----
  {
    int4* dst = (int4*)Sb;
#pragma unroll
    for (int i = 0; i < 4; ++i) {
      const int idx = tid + i * 256;
      if (idx < KB2_U16 / 8) dst[idx] = bfw[i];
    }
  }
  __syncthreads();
  // bf frags to registers: ds_read that CANNOT be rematerialized past the
  // next barrier (LDS is overwritten by slab staging)
  short8 bf[14];
#pragma unroll
  for (int p = 0; p < 14; ++p)
    bf[p] = *(const short8*)(Sb + p * 1024 + grp * 256 + r * 16);
  __syncthreads();

  // ---- scalar decode: 18 shared neighbors, then per-px rel/base ----
  const int wid = __builtin_amdgcn_readfirstlane((int)(tid >> 6));  // 0..3
  const int h = h0 + wid;
  int BPN[3][6], SVm[3][6];
#pragma unroll
  for (int nr = 0; nr < 3; ++nr) {
#pragma unroll
    for (int ci = 0; ci < 6; ++ci) {
      const int hh = h + nr - 1;
      const int ww = w0 + ci - 1;
      SVm[nr][ci] = (hh >= 0) & (hh < NB_H) & (ww >= 0) & (ww < NB_W);
      BPN[nr][ci] =
          bp[(b * NB_H + min(max(hh, 0), NB_H - 1)) * NB_W +
             min(max(ww, 0), NB_W - 1)];
    }
  }
  int RE[4][9], SBs[4][9];
#pragma unroll
  for (int px = 0; px < 4; ++px) {
    const int bpc = bp[(b * NB_H + h) * NB_W + w0 + px];
#pragma unroll
    for (int n = 0; n < 9; ++n) {
      const int nr = n / 3, dj = n % 3;
      const int ci = px + dj;
      int rel = bpc - BPN[nr][ci];
      rel = SVm[nr][ci] ? rel : 1000;         // poison -> d-check fails -> dv
      RE[px][n] = rel;
      SBs[px][n] = ((wid + nr) * 6 + ci) * SLAB_STRIDE + rel * 40;
    }
  }

  // ---- drain staging: cvt + slab writes, dv ----
#pragma unroll
  for (int k = 0; k < 18; ++k) {
    const int s = 2 * k + sg;
    s16x4 o;
    o[0] = fcvt(stv[k].x); o[1] = fcvt(stv[k].y);
    o[2] = fcvt(stv[k].z); o[3] = fcvt(stv[k].w);
    *(s16x4*)(Sb + s * SLAB_STRIDE + (q >> 2) * 40 + (q & 3) * 8) = o;
  }
  if (tid < 16) ((unsigned short*)(Sb + DV_OFF))[tid] =
      (unsigned short)fcvt(dvp[0]);
  __syncthreads();

  // ---- compute: 14 pairs x (8 LDS reads + 8 MFMA), bf reused 8x ----
  f32x4 acc00 = {0,0,0,0}, acc01 = {0,0,0,0};
  f32x4 acc10 = {0,0,0,0}, acc11 = {0,0,0,0};
  f32x4 acc20 = {0,0,0,0}, acc21 = {0,0,0,0};
  f32x4 acc30 = {0,0,0,0}, acc31 = {0,0,0,0};

#define RD_U(DST, PX, N, T)                                             \
  {                                                                     \
    const int d_ = rA + RE[PX][N] + (T);                                \
    int o_ = SBs[PX][N] + rA40 + (T) * 40;                              \
    o_ = ((unsigned)d_ < (unsigned)NB_D) ? o_ : voff_dv;                \
    DST = *(const short8*)(Sb + o_);                                    \
  }

#define RD_M(DST, PX, NE, NO, T)                                        \
  {                                                                     \
    const int re_ = halfbit ? RE[PX][NO] : RE[PX][NE];                  \
    const int sb_ = halfbit ? SBs[PX][NO] : SBs[PX][NE];                \
    const int d_ = rX + re_ + (T);                                      \
    int o_ = sb_ + rX40 + (T) * 40;                                     \
    o_ = ((unsigned)d_ < (unsigned)NB_D) ? o_ : voff_dv;                \
    DST = *(const short8*)(Sb + o_);                                    \
  }

#define RD_M13(DST, PX, NE, T)                                          \
  {                                                                     \
    const int re_ = halfbit ? 1000 : RE[PX][NE];                        \
    const int d_ = rX + re_ + (T);                                      \
    int o_ = SBs[PX][NE] + rX40 + (T) * 40;                             \
    o_ = ((unsigned)d_ < (unsigned)NB_D) ? o_ : voff_dv;                \
    DST = *(const short8*)(Sb + o_);                                    \
  }

#define MF(AC, A, P) \
  AC = __builtin_amdgcn_mfma_f32_16x16x32_bf16(A, bf[P], AC, 0, 0, 0);

#define PAIR_U(P, N)                                                    \
  {                                                                     \
    short8 a0, a1, a2, a3, a4, a5, a6, a7;                              \
    RD_U(a0, 0, N, 0) RD_U(a1, 0, N, 16)                                \
    RD_U(a2, 1, N, 0) RD_U(a3, 1, N, 16)                                \
    RD_U(a4, 2, N, 0) RD_U(a5, 2, N, 16)                                \
    RD_U(a6, 3, N, 0) RD_U(a7, 3, N, 16)                                \
    MF(acc00, a0, P) MF(acc01, a1, P) MF(acc10, a2, P) MF(acc11, a3, P) \
    MF(acc20, a4, P) MF(acc21, a5, P) MF(acc30, a6, P) MF(acc31, a7, P) \
  }

#define PAIR_M(P, NE, NO)                                               \
  {                                                                     \
    short8 a0, a1, a2, a3, a4, a5, a6, a7;                              \
    RD_M(a0, 0, NE, NO, 0) RD_M(a1, 0, NE, NO, 16)                      \
    RD_M(a2, 1, NE, NO, 0) RD_M(a3, 1, NE, NO, 16)                      \
    RD_M(a4, 2, NE, NO, 0) RD_M(a5, 2, NE, NO, 16)                      \
    RD_M(a6, 3, NE, NO, 0) RD_M(a7, 3, NE, NO, 16)                      \
    MF(acc00, a0, P) MF(acc01, a1, P) MF(acc10, a2, P) MF(acc11, a3, P) \
    MF(acc20, a4, P) MF(acc21, a5, P) MF(acc30, a6, P) MF(acc31, a7, P) \
  }

#define PAIR_M13(P, NE)                                                 \
  {                                                                     \
    short8 a0, a1, a2, a3, a4, a5, a6, a7;                              \
    RD_M13(a0, 0, NE, 0) RD_M13(a1, 0, NE, 16)                          \
    RD_M13(a2, 1, NE, 0) RD_M13(a3, 1, NE, 16)                          \
    RD_M13(a4, 2, NE, 0) RD_M13(a5, 2, NE, 16)                          \
    RD_M13(a6, 3, NE, 0) RD_M13(a7, 3, NE, 16)                          \
    MF(acc00, a0, P) MF(acc01, a1, P) MF(acc10, a2, P) MF(acc11, a3, P) \
    MF(acc20, a4, P) MF(acc21, a5, P) MF(acc30, a6, P) MF(acc31, a7, P) \
  }

  PAIR_U(0, 0);
  PAIR_U(1, 1);
  PAIR_M(2, 0, 1);
  PAIR_U(3, 2);
  PAIR_U(4, 3);
  PAIR_M(5, 2, 3);
  PAIR_U(6, 4);
  PAIR_U(7, 5);
  PAIR_M(8, 4, 5);
  PAIR_U(9, 6);
  PAIR_U(10, 7);
  PAIR_M(11, 6, 7);
  PAIR_U(12, 8);
  PAIR_M13(13, 8);

#undef RD_U
#undef RD_M
#undef RD_M13
#undef MF
#undef PAIR_U
#undef PAIR_M
#undef PAIR_M13

  // ---- stores: D layout col = lane&15 (=f), row = grp*4 + reg ----
#define STORE_PX(PX, AC0, AC1)                                          \
  {                                                                     \
    const int obase = ((b * NB_H + h) * NB_W + w0 + (PX)) * (NB_D * NB_F); \
    _Pragma("unroll")                                                   \
    for (int rr = 0; rr < 4; ++rr) {                                    \
      out[obase + (grp * 4 + rr) * NB_F + r] = AC0[rr];                 \
      out[obase + 256 + (grp * 4 + rr) * NB_F + r] = AC1[rr];           \
    }                                                                   \
  }
  STORE_PX(0, acc00, acc01)
  STORE_PX(1, acc10, acc11)
  STORE_PX(2, acc20, acc21)
  STORE_PX(3, acc30, acc31)
#undef STORE_PX
}

// ---------------- fallback (self-contained) if ws is too small -------------
__global__ __launch_bounds__(256) void sconv3d_mfma(
    const float* __restrict__ img, const int* __restrict__ bp,
    const float* __restrict__ kern, const float* __restrict__ dvp,
    float* __restrict__ out, int npix) {
  __shared__ unsigned short Kb[28 * 256];
  const int tid = threadIdx.x;
  for (int idx = tid; idx < 28 * 256; idx += 256) {
    unsigned short v = 0;
    if (idx < 27 * 256) v = (unsigned short)fcvt(kern[idx]);
    Kb[idx] = v;
  }
  __syncthreads();

  const int lane = tid & 63;
  const int grp = lane >> 4;
  const int r = lane & 15;
  const int c0 = (grp & 1) * 8;
  const int half = grp >> 1;

  short8 bfrag[14];
#pragma unroll
  for (int p = 0; p < 14; ++p) {
#pragma unroll
    for (int j = 0; j < 8; ++j) {
      const int k = 8 * grp + j;
      const int t = 2 * p + (k >> 4);
      bfrag[p][j] = (short)Kb[t * 256 + (k & 15) * 16 + r];
    }
  }

  const int pix = blockIdx.x * 4 + (tid >> 6);
  if (pix >= npix) return;
  const int b = pix / (NB_H * NB_W);
  const int rem = pix - b * (NB_H * NB_W);
  const int h = rem >> 7;
  const int w = rem & (NB_W - 1);

  const float dv = dvp[0];
  const int bpc = bp[pix];

  f32x4 acc0 = {0.f, 0.f, 0.f, 0.f};
  f32x4 acc1 = {0.f, 0.f, 0.f, 0.f};

#pragma unroll
  for (int p = 0; p < 14; ++p) {
    const int t = 2 * p + half;
    const int n = t / 3;
    const int kd = t - 3 * n;
    const int i = n / 3;
    const int j = n - 3 * i;
    const int hh = h + i - 1;
    const int ww = w + j - 1;
    const bool sv =
        (t < 27) && (hh >= 0) && (hh < NB_H) && (ww >= 0) && (ww < NB_W);
    const int hc = min(max(hh, 0), NB_H - 1);
    const int wc = min(max(ww, 0), NB_W - 1);
    const int nidx = (b * NB_H + hc) * NB_W + wc;
    const int rel = bpc - bp[nidx];
    const int base = nidx * (NB_D * NB_C);
    const int dsh = (kd - 1) + rel;

    const int ds0 = r + dsh;
    short8 a0;
    {
      float va[8];
      if (sv && (ds0 >= 0) && (ds0 < NB_D)) {
        const float4* pp = (const float4*)(img + base + ds0 * NB_C + c0);
        const float4 x = pp[0];
        const float4 y = pp[1];
        va[0] = x.x; va[1] = x.y; va[2] = x.z; va[3] = x.w;
        va[4] = y.x; va[5] = y.y; va[6] = y.z; va[7] = y.w;
      } else {
#pragma unroll
        for (int qq = 0; qq < 8; ++qq) va[qq] = dv;
      }
#pragma unroll
      for (int qq = 0; qq < 8; ++qq) a0[qq] = fcvt(va[qq]);
    }
    acc0 = __builtin_amdgcn_mfma_f32_16x16x32_bf16(a0, bfrag[p], acc0, 0, 0, 0);

    const int ds1 = ds0 + 16;
    short8 a1;
    {
      float va[8];
      if (sv && (ds1 >= 0) && (ds1 < NB_D)) {
        const float4* pp = (const float4*)(img + base + ds1 * NB_C + c0);
        const float4 x = pp[0];
        const float4 y = pp[1];
        va[0] = x.x; va[1] = x.y; va[2] = x.z; va[3] = x.w;
        va[4] = y.x; va[5] = y.y; va[6] = y.z; va[7] = y.w;
      } else {
#pragma unroll
        for (int qq = 0; qq < 8; ++qq) va[qq] = dv;
      }
#pragma unroll
      for (int qq = 0; qq < 8; ++qq) a1[qq] = fcvt(va[qq]);
    }
    acc1 = __builtin_amdgcn_mfma_f32_16x16x32_bf16(a1, bfrag[p], acc1, 0, 0, 0);
  }

  const int obase = pix * (NB_D * NB_F);
#pragma unroll
  for (int rr = 0; rr < 4; ++rr) {
    out[obase + (grp * 4 + rr) * NB_F + r] = acc0[rr];
    out[obase + (grp * 4 + rr + 16) * NB_F + r] = acc1[rr];
  }
}

extern "C" void kernel_launch(void* const* d_in, const int* in_sizes, int n_in,
                              void* d_out, int out_size, void* d_ws, size_t ws_size,
                              hipStream_t stream) {
  const float* img = (const float*)d_in[0];
  const int* bp = (const int*)d_in[1];
  const float* kern = (const float*)d_in[2];
  const float* dvp = (const float*)d_in[3];
  float* out = (float*)d_out;

  if (ws_size >= WS_NEED) {
    unsigned short* kb2 = (unsigned short*)d_ws;
    sconv3d_wprep<<<28, 256, 0, stream>>>(kern, kb2);
    sconv3d_fused7<<<NPIX / 16, 256, 0, stream>>>(img, bp, kb2, dvp, out);
  } else {
    sconv3d_mfma<<<NPIX / 4, 256, 0, stream>>>(img, bp, kern, dvp, out, NPIX);
  }
}

// Round 16
// 54.126 us; speedup vs baseline: 1.4257x; 1.4257x over previous
//
#include <hip/hip_runtime.h>
#include <hip/hip_bf16.h>

typedef __attribute__((ext_vector_type(8))) short short8;
typedef __attribute__((ext_vector_type(4))) short s16x4;
typedef __attribute__((ext_vector_type(4))) float f32x4;

#define NB_H 96
#define NB_W 128
#define NB_D 32
#define NB_C 16
#define NB_F 16
#define NPIX (2 * NB_H * NB_W)                  // 24576
#define SLAB_STRIDE 1280                        // 32 rows * 40 B (32 data + 8 pad)
#define IMGPAD ((size_t)NPIX * SLAB_STRIDE)     // 31,457,280 B
#define KB2_U16 (14 * 512)                      // 7168 u16 = 14336 B
#define WS_NEED (IMGPAD + (size_t)KB2_U16 * 2)
#define NSLAB 24                                // 4h x 6w (2x4 px tile + halo)
#define DV_OFF (NSLAB * SLAB_STRIDE)            // 30720
#define KB_OFF (DV_OFF + 64)                    // 30784
#define LDS_BYTES (KB_OFF + KB2_U16 * 2)        // 45120

// fp32 -> bf16 RNE
static __device__ __forceinline__ short fcvt(float f) {
  return (short)__builtin_bit_cast(unsigned short, __float2bfloat16(f));
}

// async global->LDS copies (LDS dest = uniform base + lane*size)
static __device__ __forceinline__ void gl_lds16(const void* g, void* l) {
  __builtin_amdgcn_global_load_lds(
      (const __attribute__((address_space(1))) unsigned int*)g,
      (__attribute__((address_space(3))) unsigned int*)l, 16, 0, 0);
}
static __device__ __forceinline__ void gl_lds4(const void* g, void* l) {
  __builtin_amdgcn_global_load_lds(
      (const __attribute__((address_space(1))) unsigned int*)g,
      (__attribute__((address_space(3))) unsigned int*)l, 4, 0, 0);
}

// Pair table: p=3q+m (q=0..3): m=0 -> taps(6q,6q+1) [UNIF n=2q, kd=0/1];
// m=1 -> (6q+3,6q+4) [UNIF n=2q+1]; m=2 -> (6q+2,6q+5) [MIX kd=2].
// p=12 -> (24,25) [UNIF n=8]. p=13 -> (26,pad). tap t = n*3+kd.

// ---- prepass: image -> padded-slab bf16 in ws; kern -> B-frag layout ------
__global__ __launch_bounds__(256) void sconv3d_prep(
    const float* __restrict__ img, const float* __restrict__ kern,
    char* __restrict__ wsc) {
  const int tid = threadIdx.x;
  if (blockIdx.x < NPIX / 16) {
    const int pix = blockIdx.x * 16 + (tid >> 4);
    const int j = tid & 15;
    const float* src = img + (size_t)pix * (NB_D * NB_C);
    char* dst = wsc + (size_t)pix * SLAB_STRIDE;
#pragma unroll
    for (int k = 0; k < 10; ++k) {
      const int c = j + k * 16;              // 8B chunk 0..159
      const int row = c / 5, cc = c - 5 * row;
      s16x4 o = {0, 0, 0, 0};
      if (cc < 4) {
        const float4 v = *(const float4*)(src + row * 16 + cc * 4);
        o[0] = fcvt(v.x); o[1] = fcvt(v.y);
        o[2] = fcvt(v.z); o[3] = fcvt(v.w);
      }
      *(s16x4*)(dst + c * 8) = o;
    }
  } else {
    const int i = (blockIdx.x - NPIX / 16) * 256 + tid;   // 0..7167
    const int p = i >> 9;
    const int g = (i >> 7) & 3;
    const int f = (i >> 3) & 15;
    const int jj = i & 7;
    const int k = g * 8 + jj;
    int lo, hi;
    if (p < 12) {
      const int q = p / 3, m = p % 3;
      lo = (m == 0) ? 6 * q : (m == 1) ? 6 * q + 3 : 6 * q + 2;
      hi = (m == 0) ? 6 * q + 1 : (m == 1) ? 6 * q + 4 : 6 * q + 5;
    } else if (p == 12) { lo = 24; hi = 25; }
    else { lo = 26; hi = -1; }
    const int t = (k < 16) ? lo : hi;
    const int c = k & 15;
    ((unsigned short*)(wsc + IMGPAD))[i] =
        (t >= 0) ? (unsigned short)fcvt(kern[(t * 16 + c) * 16 + f])
                 : (unsigned short)0;
  }
}

// ---- main: 2x4-px tile, 256 thr, global_load_lds staging, r11 pipeline ----
__global__ __launch_bounds__(256, 4) void sconv3d_glds(
    const char* __restrict__ wsc, const int* __restrict__ bp,
    const float* __restrict__ dvp, float* __restrict__ out) {
  __shared__ char Sb[LDS_BYTES];
  const int tid = threadIdx.x;
  const int lane = tid & 63;
  const int r = lane & 15;          // A: d row; B/D: f column
  const int grp = lane >> 4;        // 0..3
  const int vc = (grp & 1) * 16;    // byte offset of c-slice within 32B row
  const int halfbit = grp >> 1;     // K half: 0 -> tap lo, 1 -> tap hi
  const int rA = r + halfbit - 1;   // depth row pre-rel, kd=(0,1) pairs
  const int rX = r + 1;             // depth row pre-rel, kd=2 pairs
  const int voff_dv = DV_OFF + vc;

  // tile decode, XCD-chunked bijective swizzle: 3072 = 8 * 384
  const int bid = (blockIdx.x & 7) * 384 + (blockIdx.x >> 3);
  const int b = bid >= 1536;
  const int rem = bid - b * 1536;
  const int h0 = (rem >> 5) * 2;              // 48 h-tiles
  const int w0 = (rem & 31) * 4;              // 32 w-tiles

  const int wk = __builtin_amdgcn_readfirstlane((int)(tid >> 6));  // 0..3

  // ---- issue all staging copies (fire-and-forget, zero VGPR) ----
  {
    const int hh = min(max(h0 + wk - 1, 0), NB_H - 1);
#pragma unroll
    for (int dw = 0; dw < 6; ++dw) {
      const int ww = min(max(w0 + dw - 1, 0), NB_W - 1);
      const int nidx = (b * NB_H + hh) * NB_W + ww;
      const char* src = wsc + (size_t)nidx * SLAB_STRIDE;
      char* dst = Sb + (wk * 6 + dw) * SLAB_STRIDE;
      gl_lds16(src + lane * 16, dst);
      gl_lds4(src + 1024 + lane * 4, dst + 1024);
    }
#pragma unroll
    for (int i = 0; i < 4; ++i) {
      const int idx = wk + 4 * i;             // 0..13 over 4 waves
      if (idx < 14)
        gl_lds16(wsc + IMGPAD + idx * 1024 + lane * 16, Sb + KB_OFF + idx * 1024);
    }
  }
  const float dvf = dvp[0];

  // ---- per-wave pixel + scalar decode (overlaps copy latency) ----
  const int w = w0 + wk;
  const int pixA = (b * NB_H + h0) * NB_W + w;
  const int pixB = pixA + NB_W;
  const int bpcA = bp[pixA];
  const int bpcB = bp[pixB];

#define CALCN(PH, BPC, DI, DJ, SV, BA, RE)                              \
  {                                                                     \
    const int hh = h0 + (PH) + (DI), ww = w + (DJ);                     \
    SV = (hh >= 0) & (hh < NB_H) & (ww >= 0) & (ww < NB_W);             \
    const int hc = min(max(hh, 0), NB_H - 1);                           \
    const int wc = min(max(ww, 0), NB_W - 1);                           \
    RE = (BPC)-bp[(b * NB_H + hc) * NB_W + wc];                         \
    BA = (((PH) + (DI) + 1) * 6 + wk + (DJ) + 1) * SLAB_STRIDE;         \
  }

  int Asv0, Aba0, Are0, Asv1, Aba1, Are1, Asv2, Aba2, Are2;
  int Asv3, Aba3, Are3, Asv4, Aba4, Are4, Asv5, Aba5, Are5;
  int Asv6, Aba6, Are6, Asv7, Aba7, Are7, Asv8, Aba8, Are8;
  int Bsv0, Bba0, Bre0, Bsv1, Bba1, Bre1, Bsv2, Bba2, Bre2;
  int Bsv3, Bba3, Bre3, Bsv4, Bba4, Bre4, Bsv5, Bba5, Bre5;
  int Bsv6, Bba6, Bre6, Bsv7, Bba7, Bre7, Bsv8, Bba8, Bre8;
  CALCN(0, bpcA, -1, -1, Asv0, Aba0, Are0);
  CALCN(0, bpcA, -1, 0, Asv1, Aba1, Are1);
  CALCN(0, bpcA, -1, 1, Asv2, Aba2, Are2);
  CALCN(0, bpcA, 0, -1, Asv3, Aba3, Are3);
  CALCN(0, bpcA, 0, 0, Asv4, Aba4, Are4);
  CALCN(0, bpcA, 0, 1, Asv5, Aba5, Are5);
  CALCN(0, bpcA, 1, -1, Asv6, Aba6, Are6);
  CALCN(0, bpcA, 1, 0, Asv7, Aba7, Are7);
  CALCN(0, bpcA, 1, 1, Asv8, Aba8, Are8);
  CALCN(1, bpcB, -1, -1, Bsv0, Bba0, Bre0);
  CALCN(1, bpcB, -1, 0, Bsv1, Bba1, Bre1);
  CALCN(1, bpcB, -1, 1, Bsv2, Bba2, Bre2);
  CALCN(1, bpcB, 0, -1, Bsv3, Bba3, Bre3);
  CALCN(1, bpcB, 0, 0, Bsv4, Bba4, Bre4);
  CALCN(1, bpcB, 0, 1, Bsv5, Bba5, Bre5);
  CALCN(1, bpcB, 1, -1, Bsv6, Bba6, Bre6);
  CALCN(1, bpcB, 1, 0, Bsv7, Bba7, Bre7);
  CALCN(1, bpcB, 1, 1, Bsv8, Bba8, Bre8);
#undef CALCN

  if (tid < 16) ((unsigned short*)(Sb + DV_OFF))[tid] =
      (unsigned short)fcvt(dvf);

  __syncthreads();   // drains vmcnt (global_load_lds) + lgkm before barrier

  f32x4 accA0 = {0.f, 0.f, 0.f, 0.f}, accA1 = {0.f, 0.f, 0.f, 0.f};
  f32x4 accB0 = {0.f, 0.f, 0.f, 0.f}, accB1 = {0.f, 0.f, 0.f, 0.f};

  short8 Xa0, Xa1, Xb0, Xb1, Ya0, Ya1, Yb0, Yb1;

#define LOADQ(S, DS0A, BAA, SVA, DS0B, BAB, SVB)                        \
  {                                                                     \
    int d_, o_;                                                         \
    d_ = (DS0A);      o_ = (BAA) + d_ * 40 + vc;                        \
    o_ = ((SVA) && (unsigned)d_ < NB_D) ? o_ : voff_dv;                 \
    S##a0 = *(const short8*)(Sb + o_);                                  \
    d_ = (DS0A) + 16; o_ = (BAA) + d_ * 40 + vc;                        \
    o_ = ((SVA) && (unsigned)d_ < NB_D) ? o_ : voff_dv;                 \
    S##a1 = *(const short8*)(Sb + o_);                                  \
    d_ = (DS0B);      o_ = (BAB) + d_ * 40 + vc;                        \
    o_ = ((SVB) && (unsigned)d_ < NB_D) ? o_ : voff_dv;                 \
    S##b0 = *(const short8*)(Sb + o_);                                  \
    d_ = (DS0B) + 16; o_ = (BAB) + d_ * 40 + vc;                        \
    o_ = ((SVB) && (unsigned)d_ < NB_D) ? o_ : voff_dv;                 \
    S##b1 = *(const short8*)(Sb + o_);                                  \
  }

#define LOAD_U(S, N) \
  LOADQ(S, rA + Are##N, Aba##N, Asv##N, rA + Bre##N, Bba##N, Bsv##N)

#define LOAD_M(S, NE, NO)                                               \
  {                                                                     \
    const int asv = halfbit ? Asv##NO : Asv##NE;                        \
    const int aba = halfbit ? Aba##NO : Aba##NE;                        \
    const int are = halfbit ? Are##NO : Are##NE;                        \
    const int bsv = halfbit ? Bsv##NO : Bsv##NE;                        \
    const int bba = halfbit ? Bba##NO : Bba##NE;                        \
    const int bre = halfbit ? Bre##NO : Bre##NE;                        \
    LOADQ(S, rX + are, aba, asv, rX + bre, bba, bsv)                    \
  }

#define LOAD_M13(S, NE)                                                 \
  {                                                                     \
    const int asv = halfbit ? 0 : Asv##NE;                              \
    const int bsv = halfbit ? 0 : Bsv##NE;                              \
    LOADQ(S, rX + Are##NE, Aba##NE, asv, rX + Bre##NE, Bba##NE, bsv)    \
  }

#define FMA4(P, S)                                                      \
  {                                                                     \
    const short8 bfv = *(const short8*)(Sb + KB_OFF + (P) * 1024 +      \
                                        grp * 256 + r * 16);            \
    accA0 = __builtin_amdgcn_mfma_f32_16x16x32_bf16(S##a0, bfv, accA0, 0, 0, 0); \
    accA1 = __builtin_amdgcn_mfma_f32_16x16x32_bf16(S##a1, bfv, accA1, 0, 0, 0); \
    accB0 = __builtin_amdgcn_mfma_f32_16x16x32_bf16(S##b0, bfv, accB0, 0, 0, 0); \
    accB1 = __builtin_amdgcn_mfma_f32_16x16x32_bf16(S##b1, bfv, accB1, 0, 0, 0); \
  }

  // pipelined: load pair p+1 before consuming pair p
  LOAD_U(X, 0);                    // p0
  LOAD_U(Y, 1);                    // p1
  FMA4(0, X);  LOAD_M(X, 0, 1);    // p2
  FMA4(1, Y);  LOAD_U(Y, 2);       // p3
  FMA4(2, X);  LOAD_U(X, 3);       // p4
  FMA4(3, Y);  LOAD_M(Y, 2, 3);    // p5
  FMA4(4, X);  LOAD_U(X, 4);       // p6
  FMA4(5, Y);  LOAD_U(Y, 5);       // p7
  FMA4(6, X);  LOAD_M(X, 4, 5);    // p8
  FMA4(7, Y);  LOAD_U(Y, 6);       // p9
  FMA4(8, X);  LOAD_U(X, 7);       // p10
  FMA4(9, Y);  LOAD_M(Y, 6, 7);    // p11
  FMA4(10, X); LOAD_U(X, 8);       // p12
  FMA4(11, Y); LOAD_M13(Y, 8);     // p13
  FMA4(12, X);
  FMA4(13, Y);

#undef LOADQ
#undef LOAD_U
#undef LOAD_M
#undef LOAD_M13
#undef FMA4

  // D layout: col = lane&15 (=f), row = grp*4 + reg
  const int obaseA = pixA * (NB_D * NB_F);
  const int obaseB = pixB * (NB_D * NB_F);
#pragma unroll
  for (int rr = 0; rr < 4; ++rr) {
    out[obaseA + (grp * 4 + rr) * NB_F + r] = accA0[rr];
    out[obaseA + (grp * 4 + rr + 16) * NB_F + r] = accA1[rr];
    out[obaseB + (grp * 4 + rr) * NB_F + r] = accB0[rr];
    out[obaseB + (grp * 4 + rr + 16) * NB_F + r] = accB1[rr];
  }
}

// ---------------- fallback (self-contained) if ws is too small -------------
__global__ __launch_bounds__(256) void sconv3d_mfma(
    const float* __restrict__ img, const int* __restrict__ bp,
    const float* __restrict__ kern, const float* __restrict__ dvp,
    float* __restrict__ out, int npix) {
  __shared__ unsigned short Kb[28 * 256];
  const int tid = threadIdx.x;
  for (int idx = tid; idx < 28 * 256; idx += 256) {
    unsigned short v = 0;
    if (idx < 27 * 256) v = (unsigned short)fcvt(kern[idx]);
    Kb[idx] = v;
  }
  __syncthreads();

  const int lane = tid & 63;
  const int grp = lane >> 4;
  const int r = lane & 15;
  const int c0 = (grp & 1) * 8;
  const int half = grp >> 1;

  short8 bfrag[14];
#pragma unroll
  for (int p = 0; p < 14; ++p) {
#pragma unroll
    for (int j = 0; j < 8; ++j) {
      const int k = 8 * grp + j;
      const int t = 2 * p + (k >> 4);
      bfrag[p][j] = (short)Kb[t * 256 + (k & 15) * 16 + r];
    }
  }

  const int pix = blockIdx.x * 4 + (tid >> 6);
  if (pix >= npix) return;
  const int b = pix / (NB_H * NB_W);
  const int rem = pix - b * (NB_H * NB_W);
  const int h = rem >> 7;
  const int w = rem & (NB_W - 1);

  const float dv = dvp[0];
  const int bpc = bp[pix];

  f32x4 acc0 = {0.f, 0.f, 0.f, 0.f};
  f32x4 acc1 = {0.f, 0.f, 0.f, 0.f};

#pragma unroll
  for (int p = 0; p < 14; ++p) {
    const int t = 2 * p + half;
    const int n = t / 3;
    const int kd = t - 3 * n;
    const int i = n / 3;
    const int j = n - 3 * i;
    const int hh = h + i - 1;
    const int ww = w + j - 1;
    const bool sv =
        (t < 27) && (hh >= 0) && (hh < NB_H) && (ww >= 0) && (ww < NB_W);
    const int hc = min(max(hh, 0), NB_H - 1);
    const int wc = min(max(ww, 0), NB_W - 1);
    const int nidx = (b * NB_H + hc) * NB_W + wc;
    const int rel = bpc - bp[nidx];
    const int base = nidx * (NB_D * NB_C);
    const int dsh = (kd - 1) + rel;

    const int ds0 = r + dsh;
    short8 a0;
    {
      float va[8];
      if (sv && (ds0 >= 0) && (ds0 < NB_D)) {
        const float4* pp = (const float4*)(img + base + ds0 * NB_C + c0);
        const float4 x = pp[0];
        const float4 y = pp[1];
        va[0] = x.x; va[1] = x.y; va[2] = x.z; va[3] = x.w;
        va[4] = y.x; va[5] = y.y; va[6] = y.z; va[7] = y.w;
      } else {
#pragma unroll
        for (int qq = 0; qq < 8; ++qq) va[qq] = dv;
      }
#pragma unroll
      for (int qq = 0; qq < 8; ++qq) a0[qq] = fcvt(va[qq]);
    }
    acc0 = __builtin_amdgcn_mfma_f32_16x16x32_bf16(a0, bfrag[p], acc0, 0, 0, 0);

    const int ds1 = ds0 + 16;
    short8 a1;
    {
      float va[8];
      if (sv && (ds1 >= 0) && (ds1 < NB_D)) {
        const float4* pp = (const float4*)(img + base + ds1 * NB_C + c0);
        const float4 x = pp[0];
        const float4 y = pp[1];
        va[0] = x.x; va[1] = x.y; va[2] = x.z; va[3] = x.w;
        va[4] = y.x; va[5] = y.y; va[6] = y.z; va[7] = y.w;
      } else {
#pragma unroll
        for (int qq = 0; qq < 8; ++qq) va[qq] = dv;
      }
#pragma unroll
      for (int qq = 0; qq < 8; ++qq) a1[qq] = fcvt(va[qq]);
    }
    acc1 = __builtin_amdgcn_mfma_f32_16x16x32_bf16(a1, bfrag[p], acc1, 0, 0, 0);
  }

  const int obase = pix * (NB_D * NB_F);
#pragma unroll
  for (int rr = 0; rr < 4; ++rr) {
    out[obase + (grp * 4 + rr) * NB_F + r] = acc0[rr];
    out[obase + (grp * 4 + rr + 16) * NB_F + r] = acc1[rr];
  }
}

extern "C" void kernel_launch(void* const* d_in, const int* in_sizes, int n_in,
                              void* d_out, int out_size, void* d_ws, size_t ws_size,
                              hipStream_t stream) {
  const float* img = (const float*)d_in[0];
  const int* bp = (const int*)d_in[1];
  const float* kern = (const float*)d_in[2];
  const float* dvp = (const float*)d_in[3];
  float* out = (float*)d_out;

  if (ws_size >= WS_NEED) {
    char* wsc = (char*)d_ws;
    sconv3d_prep<<<NPIX / 16 + 28, 256, 0, stream>>>(img, kern, wsc);
    sconv3d_glds<<<NPIX / 8, 256, 0, stream>>>(wsc, bp, dvp, out);
  } else {
    sconv3d_mfma<<<NPIX / 4, 256, 0, stream>>>(img, bp, kern, dvp, out, NPIX);
  }
}